// Round 5
// baseline (592.639 us; speedup 1.0000x reference)
//
#include <hip/hip_runtime.h>
#include <cstdint>

typedef __attribute__((ext_vector_type(8))) short bf16x8;
typedef __attribute__((ext_vector_type(4))) float f32x4;
typedef __attribute__((ext_vector_type(2))) unsigned int u32x2;

#define B_   16
#define C_   512
#define HW_  4096
#define M3_  384
#define HWP_ 1024
#define CV_  256

__device__ __forceinline__ unsigned short f2b(float f) {
  union { float f; unsigned u; } v; v.f = f;
  unsigned r = v.u + 0x7fffu + ((v.u >> 16) & 1u);   // RNE
  return (unsigned short)(r >> 16);
}
__device__ __forceinline__ float b2f(unsigned short b) {
  union { unsigned u; float f; } v; v.u = ((unsigned)b) << 16;
  return v.f;
}
__device__ __forceinline__ f32x4 mfma16(bf16x8 a, bf16x8 b, f32x4 c) {
  return __builtin_amdgcn_mfma_f32_16x16x32_bf16(a, b, c, 0, 0, 0);
}

// ---------------------------------------------------------------- K0: x [b][c][n] f32 -> xb [b][n][c] bf16
__global__ __launch_bounds__(256) void k_transpose(const float* __restrict__ x,
                                                   unsigned short* __restrict__ xb) {
  __shared__ unsigned short t[64][66];
  const int b = blockIdx.z, k0 = blockIdx.y * 64, n0 = blockIdx.x * 64;
  const float* xp = x + (size_t)b * C_ * HW_;
  const int ln = threadIdx.x & 63, g = threadIdx.x >> 6;
  for (int kk = g; kk < 64; kk += 4)
    t[kk][ln] = f2b(xp[(size_t)(k0 + kk) * HW_ + n0 + ln]);
  __syncthreads();
  unsigned short* xo = xb + (size_t)b * HW_ * C_;
  for (int nn = g; nn < 64; nn += 4)
    xo[(size_t)(n0 + nn) * C_ + k0 + ln] = t[ln][nn];
}

// ---------------------------------------------------------------- K0b: transpose the 4 weight matrices (f32)
__global__ __launch_bounds__(256) void k_wtrans(
    const float* __restrict__ Wq, const float* __restrict__ Wk,
    const float* __restrict__ Wv, const float* __restrict__ Wo,
    float* __restrict__ wt) {
  const float* w; int out, in; float* dst;
  switch (blockIdx.z) {
    case 0: w = Wq; out = 64;  in = 512; dst = wt;          break;
    case 1: w = Wk; out = 64;  in = 512; dst = wt + 32768;  break;
    case 2: w = Wv; out = 256; in = 512; dst = wt + 65536;  break;
    default: w = Wo; out = 512; in = 256; dst = wt + 196608; break;
  }
  const int o0 = blockIdx.y * 64, i0 = blockIdx.x * 64;
  if (o0 >= out || i0 >= in) return;
  __shared__ float t[64][65];
  const int ln = threadIdx.x & 63, g = threadIdx.x >> 6;
  for (int oo = g; oo < 64; oo += 4)
    t[oo][ln] = w[(size_t)(o0 + oo) * in + i0 + ln];
  __syncthreads();
  for (int ii = g; ii < 64; ii += 4)
    dst[(size_t)(i0 + ii) * out + o0 + ln] = t[ln][ii];
}

// ---------------------------------------------------------------- K1: spectral norm (1 block per matrix)
__device__ __forceinline__ float block_reduce_sum512(float val, float* red) {
#pragma unroll
  for (int off = 32; off > 0; off >>= 1) val += __shfl_down(val, off);
  __syncthreads();
  if ((threadIdx.x & 63) == 0) red[threadIdx.x >> 6] = val;
  __syncthreads();
  float s = 0.f;
#pragma unroll
  for (int i = 0; i < 8; ++i) s += red[i];
  return s;
}

__global__ __launch_bounds__(512) void k_specnorm(
    const float* __restrict__ Wq, const float* __restrict__ Wk,
    const float* __restrict__ Wv, const float* __restrict__ Wo,
    const float* __restrict__ wt,
    unsigned short* __restrict__ wqkv, unsigned short* __restrict__ wob) {
  __shared__ float u[512], v[512];
  __shared__ float red[8];
  const float* w; const float* wT; int out, in; unsigned short* dst;
  switch (blockIdx.x) {
    case 0: w = Wq; wT = wt;          out = 64;  in = 512; dst = wqkv;             break;
    case 1: w = Wk; wT = wt + 32768;  out = 64;  in = 512; dst = wqkv + 64 * 512;  break;
    case 2: w = Wv; wT = wt + 65536;  out = 256; in = 512; dst = wqkv + 128 * 512; break;
    default: w = Wo; wT = wt + 196608; out = 512; in = 256; dst = wob;             break;
  }
  const int tid = threadIdx.x;
  const float rs = rsqrtf((float)out);
  for (int i = tid; i < out; i += 512) u[i] = rs;
  __syncthreads();
  for (int it = 0; it < 5; ++it) {
    for (int c = tid; c < in; c += 512) {
      float a0 = 0.f, a1 = 0.f, a2 = 0.f, a3 = 0.f;
      for (int o = 0; o < out; o += 4) {
        a0 += w[(size_t)o * in + c] * u[o];
        a1 += w[(size_t)(o + 1) * in + c] * u[o + 1];
        a2 += w[(size_t)(o + 2) * in + c] * u[o + 2];
        a3 += w[(size_t)(o + 3) * in + c] * u[o + 3];
      }
      v[c] = (a0 + a1) + (a2 + a3);
    }
    __syncthreads();
    float ss = 0.f;
    for (int c = tid; c < in; c += 512) ss += v[c] * v[c];
    ss = block_reduce_sum512(ss, red);
    const float sv = 1.f / (sqrtf(ss) + 1e-12f);
    for (int c = tid; c < in; c += 512) v[c] *= sv;
    __syncthreads();
    for (int o = tid; o < out; o += 512) {
      float a0 = 0.f, a1 = 0.f, a2 = 0.f, a3 = 0.f;
      for (int c = 0; c < in; c += 4) {
        a0 += wT[(size_t)c * out + o] * v[c];
        a1 += wT[(size_t)(c + 1) * out + o] * v[c + 1];
        a2 += wT[(size_t)(c + 2) * out + o] * v[c + 2];
        a3 += wT[(size_t)(c + 3) * out + o] * v[c + 3];
      }
      u[o] = (a0 + a1) + (a2 + a3);
    }
    __syncthreads();
    float su = 0.f;
    for (int o = tid; o < out; o += 512) su += u[o] * u[o];
    su = block_reduce_sum512(su, red);
    const float sv2 = 1.f / (sqrtf(su) + 1e-12f);
    for (int o = tid; o < out; o += 512) u[o] *= sv2;
    __syncthreads();
  }
  float sp = 0.f;
  for (int o = tid; o < out; o += 512) {
    float a0 = 0.f, a1 = 0.f, a2 = 0.f, a3 = 0.f;
    for (int c = 0; c < in; c += 4) {
      a0 += wT[(size_t)c * out + o] * v[c];
      a1 += wT[(size_t)(c + 1) * out + o] * v[c + 1];
      a2 += wT[(size_t)(c + 2) * out + o] * v[c + 2];
      a3 += wT[(size_t)(c + 3) * out + o] * v[c + 3];
    }
    sp += ((a0 + a1) + (a2 + a3)) * u[o];
  }
  sp = block_reduce_sum512(sp, red);
  // fold log2(e) into Wq so attention softmax can use exp2 directly
  const float oscale = (blockIdx.x == 0) ? 1.44269504f : 1.0f;
  const float inv_sigma = (1.f / sp) * oscale;
  const int total = out * in;
  for (int i = tid; i < total; i += 512) dst[i] = f2b(w[i] * inv_sigma);
}

// ---------------------------------------------------------------- K2: Yt[b][n][m] = xb[b][n][k] * wqkv[m][k]
__global__ __launch_bounds__(256) void k_gemm_qkv(
    const unsigned short* __restrict__ xb, const unsigned short* __restrict__ wqkv,
    unsigned short* __restrict__ yt) {
  __shared__ alignas(16) char smem[32768];
  unsigned short* As = (unsigned short*)smem;             // 128x64
  unsigned short* Bs = (unsigned short*)(smem + 16384);   // 128x64
  const int lid = blockIdx.x;                             // 1536 blocks
  const int swz = (lid & 7) * 192 + (lid >> 3);
  const int mt = swz % 3, rest = swz / 3;
  const int nt = rest & 31, b = rest >> 5;
  const int n0 = nt * 128, m0 = mt * 128;
  const unsigned short* Ap = xb + (size_t)b * HW_ * C_ + (size_t)n0 * C_;
  const unsigned short* Bp = wqkv + (size_t)m0 * C_;
  const int tid = threadIdx.x, lane = tid & 63, wid = tid >> 6;
  const int wn = (wid >> 1) * 64, wm = (wid & 1) * 64;
  f32x4 acc[4][4] = {};
  for (int k0 = 0; k0 < C_; k0 += 64) {
    __syncthreads();
#pragma unroll
    for (int i = 0; i < 4; ++i) {
      const int r = i * 32 + (tid >> 3);
      const int s = tid & 7, ss = s ^ (r & 7);
      *reinterpret_cast<f32x4*>(&As[r * 64 + ss * 8]) =
          *reinterpret_cast<const f32x4*>(&Ap[(size_t)r * C_ + k0 + s * 8]);
      *reinterpret_cast<f32x4*>(&Bs[r * 64 + ss * 8]) =
          *reinterpret_cast<const f32x4*>(&Bp[(size_t)r * C_ + k0 + s * 8]);
    }
    __syncthreads();
#pragma unroll
    for (int kk = 0; kk < 2; ++kk) {
      bf16x8 af[4], bfr[4];
#pragma unroll
      for (int i = 0; i < 4; ++i) {
        const int r = wn + i * 16 + (lane & 15);
        const int slot = (kk * 4 + (lane >> 4)) ^ (r & 7);
        af[i] = *reinterpret_cast<const bf16x8*>(&As[r * 64 + slot * 8]);
      }
#pragma unroll
      for (int j = 0; j < 4; ++j) {
        const int r = wm + j * 16 + (lane & 15);
        const int slot = (kk * 4 + (lane >> 4)) ^ (r & 7);
        bfr[j] = *reinterpret_cast<const bf16x8*>(&Bs[r * 64 + slot * 8]);
      }
#pragma unroll
      for (int i = 0; i < 4; ++i)
#pragma unroll
        for (int j = 0; j < 4; ++j) acc[i][j] = mfma16(af[i], bfr[j], acc[i][j]);
    }
  }
  // epilogue: 2 chunks of 64 n-rows, LDS bf16 [64][136], dwordx4 stores
  unsigned short* eps = (unsigned short*)smem;
  unsigned short* Y = yt + (size_t)b * HW_ * M3_;
#pragma unroll
  for (int h = 0; h < 2; ++h) {
    __syncthreads();
    if ((wid >> 1) == h) {
#pragma unroll
      for (int i = 0; i < 4; ++i)
#pragma unroll
        for (int j = 0; j < 4; ++j)
#pragma unroll
          for (int r = 0; r < 4; ++r) {
            const int nl = i * 16 + (lane >> 4) * 4 + r;
            const int ml = wm + j * 16 + (lane & 15);
            eps[nl * 136 + ml] = f2b(acc[i][j][r]);
          }
    }
    __syncthreads();
#pragma unroll
    for (int t = 0; t < 4; ++t) {
      const int row = t * 16 + (tid >> 4);
      const int m8 = (tid & 15) * 8;
      *reinterpret_cast<f32x4*>(&Y[(size_t)(n0 + h * 64 + row) * M3_ + m0 + m8]) =
          *reinterpret_cast<const f32x4*>(&eps[row * 136 + m8]);
    }
  }
}

// ---------------------------------------------------------------- K3a: gt[b][mp][c] = maxpool(Yt cols 64..127)
__global__ __launch_bounds__(256) void k_pool_g(const unsigned short* __restrict__ yt,
                                                unsigned short* __restrict__ gt) {
  const int b = blockIdx.y, mp0 = blockIdx.x * 64;
  const int c = threadIdx.x & 63, dm = threadIdx.x >> 6;
  const unsigned short* Y = yt + (size_t)b * HW_ * M3_;
  unsigned short* G = gt + (size_t)b * HWP_ * 64;
  for (int mm = dm; mm < 64; mm += 4) {
    const int mp = mp0 + mm;
    const int n00 = (mp >> 5) * 128 + (mp & 31) * 2;
    const float a0 = b2f(Y[(size_t)n00 * M3_ + 64 + c]);
    const float a1 = b2f(Y[(size_t)(n00 + 1) * M3_ + 64 + c]);
    const float a2 = b2f(Y[(size_t)(n00 + 64) * M3_ + 64 + c]);
    const float a3 = b2f(Y[(size_t)(n00 + 65) * M3_ + 64 + c]);
    G[(size_t)mp * 64 + c] = f2b(fmaxf(fmaxf(a0, a1), fmaxf(a2, a3)));
  }
}

// ---------------------------------------------------------------- K3b: vt[b][cv][mp] = maxpool(Yt cols 128..383)^T
__global__ __launch_bounds__(256) void k_pool_vt(const unsigned short* __restrict__ yt,
                                                 unsigned short* __restrict__ vt) {
  __shared__ unsigned short t[64][66];
  const int b = blockIdx.z, mp0 = blockIdx.x * 64, cv0 = blockIdx.y * 64;
  const unsigned short* Y = yt + (size_t)b * HW_ * M3_;
  const int c = threadIdx.x & 63, dm = threadIdx.x >> 6;
  for (int mm = dm; mm < 64; mm += 4) {
    const int mp = mp0 + mm;
    const int n00 = (mp >> 5) * 128 + (mp & 31) * 2;
    const float a0 = b2f(Y[(size_t)n00 * M3_ + 128 + cv0 + c]);
    const float a1 = b2f(Y[(size_t)(n00 + 1) * M3_ + 128 + cv0 + c]);
    const float a2 = b2f(Y[(size_t)(n00 + 64) * M3_ + 128 + cv0 + c]);
    const float a3 = b2f(Y[(size_t)(n00 + 65) * M3_ + 128 + cv0 + c]);
    t[mm][c] = f2b(fmaxf(fmaxf(a0, a1), fmaxf(a2, a3)));
  }
  __syncthreads();
  unsigned short* V = vt + (size_t)b * CV_ * HWP_;
  for (int cc = dm; cc < 64; cc += 4)
    V[(size_t)(cv0 + cc) * HWP_ + mp0 + c] = t[c][cc];
}

// ---------------------------------------------------------------- K4: flash attention, barrier-free
// K/V/Q fragments loaded DIRECTLY from global (L1/L2-resident; no LDS staging,
// no __syncthreads in the loop). Only P (per-wave, 2KB) lives in LDS.
// Q pre-scaled by log2(e); softmax in log2 domain with defer-max (T13).
__global__ __launch_bounds__(256, 4) void k_attn(
    const unsigned short* __restrict__ yt, const unsigned short* __restrict__ gt,
    const unsigned short* __restrict__ vt, unsigned short* __restrict__ oat) {
  __shared__ alignas(16) char smem[33792];   // loop: P = 4 waves x 2KB; epilogue: 64x264 bf16
  const int lid = blockIdx.x;                // 1024 blocks
  const int swz = (lid & 7) * 128 + (lid >> 3);
  const int q0 = (swz & 63) * 64, b = swz >> 6;
  const int tid = threadIdx.x, lane = tid & 63, wid = tid >> 6;
  const int q = lane & 15, g = lane >> 4;
  const unsigned short* Qg = yt + (size_t)b * HW_ * M3_ + (size_t)q0 * M3_;
  const unsigned short* Gg = gt + (size_t)b * HWP_ * 64;
  const unsigned short* Vg = vt + (size_t)b * CV_ * HWP_;
  unsigned short* P = (unsigned short*)smem + wid * 1024;  // 16 q-rows x 64 kv
  // Q fragments direct from global, held in regs for the whole kernel
  bf16x8 qf[2];
#pragma unroll
  for (int kk = 0; kk < 2; ++kk)
    qf[kk] = *reinterpret_cast<const bf16x8*>(&Qg[(size_t)(wid * 16 + q) * M3_ + kk * 32 + g * 8]);
  f32x4 oacc[16] = {};
  float m_run = -1e30f, l_run = 0.f;
  for (int kv0 = 0; kv0 < HWP_; kv0 += 64) {
    // QK^T (swapped): kf direct from global; sacc rows kv, col q
    f32x4 sacc[4] = {};
#pragma unroll
    for (int kk = 0; kk < 2; ++kk) {
      bf16x8 kf[4];
#pragma unroll
      for (int i = 0; i < 4; ++i)
        kf[i] = *reinterpret_cast<const bf16x8*>(&Gg[(size_t)(kv0 + i * 16 + q) * 64 + kk * 32 + g * 8]);
#pragma unroll
      for (int i = 0; i < 4; ++i) sacc[i] = mfma16(kf[i], qf[kk], sacc[i]);
    }
    // online softmax (log2 domain), defer-max
    float tmax = -1e30f;
#pragma unroll
    for (int i = 0; i < 4; ++i)
#pragma unroll
      for (int r = 0; r < 4; ++r) tmax = fmaxf(tmax, sacc[i][r]);
    tmax = fmaxf(tmax, __shfl_xor(tmax, 16));
    tmax = fmaxf(tmax, __shfl_xor(tmax, 32));
    if (__any(tmax > m_run + 11.0f)) {
      const float mnew = fmaxf(m_run, tmax);
      const float alpha = exp2f(m_run - mnew);
      m_run = mnew;
      l_run *= alpha;
      float al[4];
#pragma unroll
      for (int r = 0; r < 4; ++r) al[r] = __shfl(alpha, g * 4 + r);
#pragma unroll
      for (int j = 0; j < 16; ++j) {
        oacc[j][0] *= al[0]; oacc[j][1] *= al[1];
        oacc[j][2] *= al[2]; oacc[j][3] *= al[3];
      }
    }
    float lsum = 0.f;
#pragma unroll
    for (int i = 0; i < 4; ++i) {
      const float p0 = exp2f(sacc[i][0] - m_run);
      const float p1 = exp2f(sacc[i][1] - m_run);
      const float p2 = exp2f(sacc[i][2] - m_run);
      const float p3 = exp2f(sacc[i][3] - m_run);
      lsum += (p0 + p1) + (p2 + p3);
      u32x2 pw;
      pw[0] = ((unsigned)f2b(p1) << 16) | f2b(p0);
      pw[1] = ((unsigned)f2b(p3) << 16) | f2b(p2);
      const int sl = (2 * i + (g >> 1)) ^ (q & 7);   // kv>>3 ^ q&7
      *reinterpret_cast<u32x2*>(&P[q * 64 + sl * 8 + (g & 1) * 4]) = pw;
    }
    lsum += __shfl_xor(lsum, 16);
    lsum += __shfl_xor(lsum, 32);
    l_run += lsum;
    // PV: pa from wave-private LDS; vf direct from global (L1/L2-resident)
#pragma unroll
    for (int kk = 0; kk < 2; ++kk) {
      const bf16x8 pa = *reinterpret_cast<const bf16x8*>(&P[q * 64 + ((kk * 4 + g) ^ (q & 7)) * 8]);
#pragma unroll
      for (int j = 0; j < 16; ++j) {
        const bf16x8 vf = *reinterpret_cast<const bf16x8*>(
            &Vg[(size_t)(j * 16 + q) * HWP_ + kv0 + kk * 32 + g * 8]);
        oacc[j] = mfma16(pa, vf, oacc[j]);
      }
    }
  }
  // epilogue: normalize, repack to LDS, dwordx4 store
  float linv[4];
  {
    const float myinv = 1.f / l_run;
#pragma unroll
    for (int r = 0; r < 4; ++r) linv[r] = __shfl(myinv, g * 4 + r);
  }
  unsigned short* eps = (unsigned short*)smem;   // 64 x 264
  __syncthreads();
#pragma unroll
  for (int j = 0; j < 16; ++j)
#pragma unroll
    for (int r = 0; r < 4; ++r) {
      const int row = wid * 16 + g * 4 + r;
      const int cv = j * 16 + q;
      eps[row * 264 + cv] = f2b(oacc[j][r] * linv[r]);
    }
  __syncthreads();
  unsigned short* O = oat + (size_t)b * HW_ * CV_ + (size_t)q0 * CV_;
#pragma unroll
  for (int t = 0; t < 8; ++t) {
    const int row = t * 8 + (tid >> 5);
    const int cv8 = (tid & 31) * 8;
    *reinterpret_cast<f32x4*>(&O[(size_t)row * CV_ + cv8]) =
        *reinterpret_cast<const f32x4*>(&eps[row * 264 + cv8]);
  }
}

// ---------------------------------------------------------------- K5: out[b][co][n] = gamma * wo@Oatt^T + x
__global__ __launch_bounds__(256) void k_gemm_out(
    const unsigned short* __restrict__ oat, const unsigned short* __restrict__ wob,
    const float* __restrict__ x, const float* __restrict__ gamma,
    float* __restrict__ out) {
  __shared__ alignas(16) char smem[32768];
  unsigned short* As = (unsigned short*)smem;
  unsigned short* Bs = (unsigned short*)(smem + 16384);
  const int lid = blockIdx.x;                              // 2048 blocks
  const int swz = (lid & 7) * 256 + (lid >> 3);
  const int ct = swz & 3, nt = (swz >> 2) & 31, b = swz >> 7;
  const int n0 = nt * 128, co0 = ct * 128;
  const unsigned short* Ap = wob + (size_t)co0 * CV_;
  const unsigned short* Bp = oat + (size_t)b * HW_ * CV_ + (size_t)n0 * CV_;
  const int tid = threadIdx.x, lane = tid & 63, wid = tid >> 6;
  const int wc = (wid >> 1) * 64, wn = (wid & 1) * 64;
  f32x4 acc[4][4] = {};
  for (int k0 = 0; k0 < CV_; k0 += 64) {
    __syncthreads();
#pragma unroll
    for (int i = 0; i < 4; ++i) {
      const int r = i * 32 + (tid >> 3);
      const int s = tid & 7, ss = s ^ (r & 7);
      *reinterpret_cast<f32x4*>(&As[r * 64 + ss * 8]) =
          *reinterpret_cast<const f32x4*>(&Ap[(size_t)r * CV_ + k0 + s * 8]);
      *reinterpret_cast<f32x4*>(&Bs[r * 64 + ss * 8]) =
          *reinterpret_cast<const f32x4*>(&Bp[(size_t)r * CV_ + k0 + s * 8]);
    }
    __syncthreads();
#pragma unroll
    for (int kk = 0; kk < 2; ++kk) {
      bf16x8 af[4], bfr[4];
#pragma unroll
      for (int i = 0; i < 4; ++i) {
        const int r = wc + i * 16 + (lane & 15);
        const int slot = (kk * 4 + (lane >> 4)) ^ (r & 7);
        af[i] = *reinterpret_cast<const bf16x8*>(&As[r * 64 + slot * 8]);
      }
#pragma unroll
      for (int j = 0; j < 4; ++j) {
        const int r = wn + j * 16 + (lane & 15);
        const int slot = (kk * 4 + (lane >> 4)) ^ (r & 7);
        bfr[j] = *reinterpret_cast<const bf16x8*>(&Bs[r * 64 + slot * 8]);
      }
#pragma unroll
      for (int i = 0; i < 4; ++i)
#pragma unroll
        for (int j = 0; j < 4; ++j) acc[i][j] = mfma16(af[i], bfr[j], acc[i][j]);
    }
  }
  // epilogue: 4 chunks of 32 co-rows; LDS f32 [32][132]; dwordx4 x-load + out-store
  float* eps = (float*)smem;
  const float g = gamma[0];
  const size_t base = (size_t)b * C_ * HW_;
#pragma unroll
  for (int h = 0; h < 4; ++h) {
    __syncthreads();
    if ((wid >> 1) == (h >> 1)) {
#pragma unroll
      for (int ii = 0; ii < 2; ++ii) {
        const int i = (h & 1) * 2 + ii;
#pragma unroll
        for (int j = 0; j < 4; ++j)
#pragma unroll
          for (int r = 0; r < 4; ++r) {
            const int col2 = ii * 16 + (lane >> 4) * 4 + r;
            const int nl = wn + j * 16 + (lane & 15);
            eps[col2 * 132 + nl] = acc[i][j][r];
          }
      }
    }
    __syncthreads();
#pragma unroll
    for (int t = 0; t < 4; ++t) {
      const int row = t * 8 + (tid >> 5);
      const int col = (tid & 31) * 4;
      const size_t goff = base + (size_t)(co0 + h * 32 + row) * HW_ + n0 + col;
      const f32x4 xv = *reinterpret_cast<const f32x4*>(&x[goff]);
      const f32x4 av = *reinterpret_cast<const f32x4*>(&eps[row * 132 + col]);
      f32x4 ov;
      ov[0] = g * av[0] + xv[0];
      ov[1] = g * av[1] + xv[1];
      ov[2] = g * av[2] + xv[2];
      ov[3] = g * av[3] + xv[3];
      *reinterpret_cast<f32x4*>(&out[goff]) = ov;
    }
  }
}

// ---------------------------------------------------------------- launcher
extern "C" void kernel_launch(void* const* d_in, const int* in_sizes, int n_in,
                              void* d_out, int out_size, void* d_ws, size_t ws_size,
                              hipStream_t stream) {
  (void)in_sizes; (void)n_in; (void)out_size; (void)ws_size;
  const float* x     = (const float*)d_in[0];
  const float* Wq    = (const float*)d_in[1];
  const float* Wk    = (const float*)d_in[2];
  const float* Wv    = (const float*)d_in[3];
  const float* Wo    = (const float*)d_in[4];
  const float* gamma = (const float*)d_in[5];
  float* out = (float*)d_out;
  char* ws = (char*)d_ws;

  unsigned short* wqkv = (unsigned short*)(ws);                 // 384*512*2
  unsigned short* wob  = (unsigned short*)(ws + 393216);        // 512*256*2
  unsigned short* xb   = (unsigned short*)(ws + 655360);        // 64MB
  unsigned short* yt   = (unsigned short*)(ws + 67764224);      // 48MB
  unsigned short* gt   = (unsigned short*)(ws + 118095872);     // 2MB
  unsigned short* vt   = (unsigned short*)(ws + 120193024);     // 8MB
  unsigned short* oat  = xb;  // alias: xb dead after k_gemm_qkv
  float* wt = (float*)yt;     // alias: wT only live during specnorm

  k_wtrans<<<dim3(8, 8, 4), 256, 0, stream>>>(Wq, Wk, Wv, Wo, wt);
  k_specnorm<<<4, 512, 0, stream>>>(Wq, Wk, Wv, Wo, wt, wqkv, wob);
  k_transpose<<<dim3(64, 8, 16), 256, 0, stream>>>(x, xb);
  k_gemm_qkv<<<1536, 256, 0, stream>>>(xb, wqkv, yt);
  k_pool_g<<<dim3(16, 16), 256, 0, stream>>>(yt, gt);
  k_pool_vt<<<dim3(16, 4, 16), 256, 0, stream>>>(yt, vt);
  k_attn<<<1024, 256, 0, stream>>>(yt, gt, vt, oat);
  k_gemm_out<<<2048, 256, 0, stream>>>(oat, wob, x, gamma, out);
}

// Round 6
// 400.046 us; speedup vs baseline: 1.4814x; 1.4814x over previous
//
#include <hip/hip_runtime.h>
#include <cstdint>

typedef __attribute__((ext_vector_type(8))) short bf16x8;
typedef __attribute__((ext_vector_type(4))) float f32x4;
typedef __attribute__((ext_vector_type(2))) unsigned int u32x2;

#define B_   16
#define C_   512
#define HW_  4096
#define M3_  384
#define HWP_ 1024
#define CV_  256

__device__ __forceinline__ unsigned short f2b(float f) {
  union { float f; unsigned u; } v; v.f = f;
  unsigned r = v.u + 0x7fffu + ((v.u >> 16) & 1u);   // RNE
  return (unsigned short)(r >> 16);
}
__device__ __forceinline__ float b2f(unsigned short b) {
  union { unsigned u; float f; } v; v.u = ((unsigned)b) << 16;
  return v.f;
}
__device__ __forceinline__ f32x4 mfma16(bf16x8 a, bf16x8 b, f32x4 c) {
  return __builtin_amdgcn_mfma_f32_16x16x32_bf16(a, b, c, 0, 0, 0);
}

// ---------------------------------------------------------------- K0: x [b][c][n] f32 -> xb [b][n][c] bf16
__global__ __launch_bounds__(256) void k_transpose(const float* __restrict__ x,
                                                   unsigned short* __restrict__ xb) {
  __shared__ unsigned short t[64][66];
  const int b = blockIdx.z, k0 = blockIdx.y * 64, n0 = blockIdx.x * 64;
  const float* xp = x + (size_t)b * C_ * HW_;
  const int ln = threadIdx.x & 63, g = threadIdx.x >> 6;
  for (int kk = g; kk < 64; kk += 4)
    t[kk][ln] = f2b(xp[(size_t)(k0 + kk) * HW_ + n0 + ln]);
  __syncthreads();
  unsigned short* xo = xb + (size_t)b * HW_ * C_;
  for (int nn = g; nn < 64; nn += 4)
    xo[(size_t)(n0 + nn) * C_ + k0 + ln] = t[ln][nn];
}

// ---------------------------------------------------------------- K0b: transpose the 4 weight matrices (f32)
__global__ __launch_bounds__(256) void k_wtrans(
    const float* __restrict__ Wq, const float* __restrict__ Wk,
    const float* __restrict__ Wv, const float* __restrict__ Wo,
    float* __restrict__ wt) {
  const float* w; int out, in; float* dst;
  switch (blockIdx.z) {
    case 0: w = Wq; out = 64;  in = 512; dst = wt;          break;
    case 1: w = Wk; out = 64;  in = 512; dst = wt + 32768;  break;
    case 2: w = Wv; out = 256; in = 512; dst = wt + 65536;  break;
    default: w = Wo; out = 512; in = 256; dst = wt + 196608; break;
  }
  const int o0 = blockIdx.y * 64, i0 = blockIdx.x * 64;
  if (o0 >= out || i0 >= in) return;
  __shared__ float t[64][65];
  const int ln = threadIdx.x & 63, g = threadIdx.x >> 6;
  for (int oo = g; oo < 64; oo += 4)
    t[oo][ln] = w[(size_t)(o0 + oo) * in + i0 + ln];
  __syncthreads();
  for (int ii = g; ii < 64; ii += 4)
    dst[(size_t)(i0 + ii) * out + o0 + ln] = t[ln][ii];
}

// ---------------------------------------------------------------- K1: spectral norm (1 block per matrix)
__device__ __forceinline__ float block_reduce_sum512(float val, float* red) {
#pragma unroll
  for (int off = 32; off > 0; off >>= 1) val += __shfl_down(val, off);
  __syncthreads();
  if ((threadIdx.x & 63) == 0) red[threadIdx.x >> 6] = val;
  __syncthreads();
  float s = 0.f;
#pragma unroll
  for (int i = 0; i < 8; ++i) s += red[i];
  return s;
}

__global__ __launch_bounds__(512) void k_specnorm(
    const float* __restrict__ Wq, const float* __restrict__ Wk,
    const float* __restrict__ Wv, const float* __restrict__ Wo,
    const float* __restrict__ wt,
    unsigned short* __restrict__ wqkv, unsigned short* __restrict__ wob) {
  __shared__ float u[512], v[512];
  __shared__ float red[8];
  const float* w; const float* wT; int out, in; unsigned short* dst;
  switch (blockIdx.x) {
    case 0: w = Wq; wT = wt;          out = 64;  in = 512; dst = wqkv;             break;
    case 1: w = Wk; wT = wt + 32768;  out = 64;  in = 512; dst = wqkv + 64 * 512;  break;
    case 2: w = Wv; wT = wt + 65536;  out = 256; in = 512; dst = wqkv + 128 * 512; break;
    default: w = Wo; wT = wt + 196608; out = 512; in = 256; dst = wob;             break;
  }
  const int tid = threadIdx.x;
  const float rs = rsqrtf((float)out);
  for (int i = tid; i < out; i += 512) u[i] = rs;
  __syncthreads();
  for (int it = 0; it < 5; ++it) {
    for (int c = tid; c < in; c += 512) {
      float a0 = 0.f, a1 = 0.f, a2 = 0.f, a3 = 0.f;
      for (int o = 0; o < out; o += 4) {
        a0 += w[(size_t)o * in + c] * u[o];
        a1 += w[(size_t)(o + 1) * in + c] * u[o + 1];
        a2 += w[(size_t)(o + 2) * in + c] * u[o + 2];
        a3 += w[(size_t)(o + 3) * in + c] * u[o + 3];
      }
      v[c] = (a0 + a1) + (a2 + a3);
    }
    __syncthreads();
    float ss = 0.f;
    for (int c = tid; c < in; c += 512) ss += v[c] * v[c];
    ss = block_reduce_sum512(ss, red);
    const float sv = 1.f / (sqrtf(ss) + 1e-12f);
    for (int c = tid; c < in; c += 512) v[c] *= sv;
    __syncthreads();
    for (int o = tid; o < out; o += 512) {
      float a0 = 0.f, a1 = 0.f, a2 = 0.f, a3 = 0.f;
      for (int c = 0; c < in; c += 4) {
        a0 += wT[(size_t)c * out + o] * v[c];
        a1 += wT[(size_t)(c + 1) * out + o] * v[c + 1];
        a2 += wT[(size_t)(c + 2) * out + o] * v[c + 2];
        a3 += wT[(size_t)(c + 3) * out + o] * v[c + 3];
      }
      u[o] = (a0 + a1) + (a2 + a3);
    }
    __syncthreads();
    float su = 0.f;
    for (int o = tid; o < out; o += 512) su += u[o] * u[o];
    su = block_reduce_sum512(su, red);
    const float sv2 = 1.f / (sqrtf(su) + 1e-12f);
    for (int o = tid; o < out; o += 512) u[o] *= sv2;
    __syncthreads();
  }
  float sp = 0.f;
  for (int o = tid; o < out; o += 512) {
    float a0 = 0.f, a1 = 0.f, a2 = 0.f, a3 = 0.f;
    for (int c = 0; c < in; c += 4) {
      a0 += wT[(size_t)c * out + o] * v[c];
      a1 += wT[(size_t)(c + 1) * out + o] * v[c + 1];
      a2 += wT[(size_t)(c + 2) * out + o] * v[c + 2];
      a3 += wT[(size_t)(c + 3) * out + o] * v[c + 3];
    }
    sp += ((a0 + a1) + (a2 + a3)) * u[o];
  }
  sp = block_reduce_sum512(sp, red);
  // fold log2(e) into Wq so attention softmax can use exp2 directly
  const float oscale = (blockIdx.x == 0) ? 1.44269504f : 1.0f;
  const float inv_sigma = (1.f / sp) * oscale;
  const int total = out * in;
  for (int i = tid; i < total; i += 512) dst[i] = f2b(w[i] * inv_sigma);
}

// ---------------------------------------------------------------- K2: Yt[b][n][m] = xb[b][n][k] * wqkv[m][k]
__global__ __launch_bounds__(256) void k_gemm_qkv(
    const unsigned short* __restrict__ xb, const unsigned short* __restrict__ wqkv,
    unsigned short* __restrict__ yt) {
  __shared__ alignas(16) char smem[32768];
  unsigned short* As = (unsigned short*)smem;             // 128x64
  unsigned short* Bs = (unsigned short*)(smem + 16384);   // 128x64
  const int lid = blockIdx.x;                             // 1536 blocks
  const int swz = (lid & 7) * 192 + (lid >> 3);
  const int mt = swz % 3, rest = swz / 3;
  const int nt = rest & 31, b = rest >> 5;
  const int n0 = nt * 128, m0 = mt * 128;
  const unsigned short* Ap = xb + (size_t)b * HW_ * C_ + (size_t)n0 * C_;
  const unsigned short* Bp = wqkv + (size_t)m0 * C_;
  const int tid = threadIdx.x, lane = tid & 63, wid = tid >> 6;
  const int wn = (wid >> 1) * 64, wm = (wid & 1) * 64;
  f32x4 acc[4][4] = {};
  for (int k0 = 0; k0 < C_; k0 += 64) {
    __syncthreads();
#pragma unroll
    for (int i = 0; i < 4; ++i) {
      const int r = i * 32 + (tid >> 3);
      const int s = tid & 7, ss = s ^ (r & 7);
      *reinterpret_cast<f32x4*>(&As[r * 64 + ss * 8]) =
          *reinterpret_cast<const f32x4*>(&Ap[(size_t)r * C_ + k0 + s * 8]);
      *reinterpret_cast<f32x4*>(&Bs[r * 64 + ss * 8]) =
          *reinterpret_cast<const f32x4*>(&Bp[(size_t)r * C_ + k0 + s * 8]);
    }
    __syncthreads();
#pragma unroll
    for (int kk = 0; kk < 2; ++kk) {
      bf16x8 af[4], bfr[4];
#pragma unroll
      for (int i = 0; i < 4; ++i) {
        const int r = wn + i * 16 + (lane & 15);
        const int slot = (kk * 4 + (lane >> 4)) ^ (r & 7);
        af[i] = *reinterpret_cast<const bf16x8*>(&As[r * 64 + slot * 8]);
      }
#pragma unroll
      for (int j = 0; j < 4; ++j) {
        const int r = wm + j * 16 + (lane & 15);
        const int slot = (kk * 4 + (lane >> 4)) ^ (r & 7);
        bfr[j] = *reinterpret_cast<const bf16x8*>(&Bs[r * 64 + slot * 8]);
      }
#pragma unroll
      for (int i = 0; i < 4; ++i)
#pragma unroll
        for (int j = 0; j < 4; ++j) acc[i][j] = mfma16(af[i], bfr[j], acc[i][j]);
    }
  }
  // epilogue: 2 chunks of 64 n-rows, LDS bf16 [64][136], dwordx4 stores
  unsigned short* eps = (unsigned short*)smem;
  unsigned short* Y = yt + (size_t)b * HW_ * M3_;
#pragma unroll
  for (int h = 0; h < 2; ++h) {
    __syncthreads();
    if ((wid >> 1) == h) {
#pragma unroll
      for (int i = 0; i < 4; ++i)
#pragma unroll
        for (int j = 0; j < 4; ++j)
#pragma unroll
          for (int r = 0; r < 4; ++r) {
            const int nl = i * 16 + (lane >> 4) * 4 + r;
            const int ml = wm + j * 16 + (lane & 15);
            eps[nl * 136 + ml] = f2b(acc[i][j][r]);
          }
    }
    __syncthreads();
#pragma unroll
    for (int t = 0; t < 4; ++t) {
      const int row = t * 16 + (tid >> 4);
      const int m8 = (tid & 15) * 8;
      *reinterpret_cast<f32x4*>(&Y[(size_t)(n0 + h * 64 + row) * M3_ + m0 + m8]) =
          *reinterpret_cast<const f32x4*>(&eps[row * 136 + m8]);
    }
  }
}

// ---------------------------------------------------------------- K3a: gt[b][mp][c] = maxpool(Yt cols 64..127)
__global__ __launch_bounds__(256) void k_pool_g(const unsigned short* __restrict__ yt,
                                                unsigned short* __restrict__ gt) {
  const int b = blockIdx.y, mp0 = blockIdx.x * 64;
  const int c = threadIdx.x & 63, dm = threadIdx.x >> 6;
  const unsigned short* Y = yt + (size_t)b * HW_ * M3_;
  unsigned short* G = gt + (size_t)b * HWP_ * 64;
  for (int mm = dm; mm < 64; mm += 4) {
    const int mp = mp0 + mm;
    const int n00 = (mp >> 5) * 128 + (mp & 31) * 2;
    const float a0 = b2f(Y[(size_t)n00 * M3_ + 64 + c]);
    const float a1 = b2f(Y[(size_t)(n00 + 1) * M3_ + 64 + c]);
    const float a2 = b2f(Y[(size_t)(n00 + 64) * M3_ + 64 + c]);
    const float a3 = b2f(Y[(size_t)(n00 + 65) * M3_ + 64 + c]);
    G[(size_t)mp * 64 + c] = f2b(fmaxf(fmaxf(a0, a1), fmaxf(a2, a3)));
  }
}

// ---------------------------------------------------------------- K3b: vt[b][cv][mp] = maxpool(Yt cols 128..383)^T
__global__ __launch_bounds__(256) void k_pool_vt(const unsigned short* __restrict__ yt,
                                                 unsigned short* __restrict__ vt) {
  __shared__ unsigned short t[64][66];
  const int b = blockIdx.z, mp0 = blockIdx.x * 64, cv0 = blockIdx.y * 64;
  const unsigned short* Y = yt + (size_t)b * HW_ * M3_;
  const int c = threadIdx.x & 63, dm = threadIdx.x >> 6;
  for (int mm = dm; mm < 64; mm += 4) {
    const int mp = mp0 + mm;
    const int n00 = (mp >> 5) * 128 + (mp & 31) * 2;
    const float a0 = b2f(Y[(size_t)n00 * M3_ + 128 + cv0 + c]);
    const float a1 = b2f(Y[(size_t)(n00 + 1) * M3_ + 128 + cv0 + c]);
    const float a2 = b2f(Y[(size_t)(n00 + 64) * M3_ + 128 + cv0 + c]);
    const float a3 = b2f(Y[(size_t)(n00 + 65) * M3_ + 128 + cv0 + c]);
    t[mm][c] = f2b(fmaxf(fmaxf(a0, a1), fmaxf(a2, a3)));
  }
  __syncthreads();
  unsigned short* V = vt + (size_t)b * CV_ * HWP_;
  for (int cc = dm; cc < 64; cc += 4)
    V[(size_t)(cv0 + cc) * HWP_ + mp0 + c] = t[c][cc];
}

// ---------------------------------------------------------------- K4: flash attention (R3 structure + occupancy)
// K,V staged in LDS (reg-prefetched double-issue); Q direct global->regs;
// P per-wave in LDS; exp2 log2-domain softmax with defer-max; 48KB LDS -> 3 blocks/CU.
__global__ __launch_bounds__(256, 3) void k_attn(
    const unsigned short* __restrict__ yt, const unsigned short* __restrict__ gt,
    const unsigned short* __restrict__ vt, unsigned short* __restrict__ oat) {
  __shared__ alignas(16) char smem[49152];
  unsigned short* Ks = (unsigned short*)smem;              // 8KB  [64][64]
  unsigned short* Vs = (unsigned short*)(smem + 8192);     // 32KB [256][64]
  unsigned short* Ps = (unsigned short*)(smem + 40960);    // 8KB  4 x [16][64]
  const int lid = blockIdx.x;                              // 1024 blocks
  const int swz = (lid & 7) * 128 + (lid >> 3);
  const int q0 = (swz & 63) * 64, b = swz >> 6;
  const int tid = threadIdx.x, lane = tid & 63, wid = tid >> 6;
  const int q = lane & 15, g = lane >> 4;
  const unsigned short* Qg = yt + (size_t)b * HW_ * M3_ + (size_t)q0 * M3_;
  const unsigned short* Gg = gt + (size_t)b * HWP_ * 64;
  const unsigned short* Vg = vt + (size_t)b * CV_ * HWP_;
  unsigned short* P = Ps + wid * 1024;                     // 16 q-rows x 64 kv
  // Q fragments direct from global, held in regs for the whole kernel
  bf16x8 qf[2];
#pragma unroll
  for (int kk = 0; kk < 2; ++kk)
    qf[kk] = *reinterpret_cast<const bf16x8*>(&Qg[(size_t)(wid * 16 + q) * M3_ + kk * 32 + g * 8]);
  // prologue: K/V tile 0 -> regs
  f32x4 kreg[2], vreg[8];
#pragma unroll
  for (int t = 0; t < 2; ++t) {
    const int i = tid + t * 256, r = i >> 3, s = i & 7;
    kreg[t] = *reinterpret_cast<const f32x4*>(&Gg[(size_t)r * 64 + s * 8]);
  }
#pragma unroll
  for (int t = 0; t < 8; ++t) {
    const int i = tid + t * 256, r = i >> 3, s = i & 7;
    vreg[t] = *reinterpret_cast<const f32x4*>(&Vg[(size_t)r * HWP_ + s * 8]);
  }
  f32x4 oacc[16] = {};
  float m_run = -1e30f, l_run = 0.f;
  for (int it = 0; it < 16; ++it) {
    __syncthreads();
#pragma unroll
    for (int t = 0; t < 2; ++t) {
      const int i = tid + t * 256, r = i >> 3, s = i & 7, ss = s ^ (r & 7);
      *reinterpret_cast<f32x4*>(&Ks[r * 64 + ss * 8]) = kreg[t];
    }
#pragma unroll
    for (int t = 0; t < 8; ++t) {
      const int i = tid + t * 256, r = i >> 3, s = i & 7, ss = s ^ (r & 7);
      *reinterpret_cast<f32x4*>(&Vs[r * 64 + ss * 8]) = vreg[t];
    }
    __syncthreads();
    if (it < 15) {  // async: issue next tile's loads, consumed next iteration
      const int kvn = (it + 1) * 64;
#pragma unroll
      for (int t = 0; t < 2; ++t) {
        const int i = tid + t * 256, r = i >> 3, s = i & 7;
        kreg[t] = *reinterpret_cast<const f32x4*>(&Gg[(size_t)(kvn + r) * 64 + s * 8]);
      }
#pragma unroll
      for (int t = 0; t < 8; ++t) {
        const int i = tid + t * 256, r = i >> 3, s = i & 7;
        vreg[t] = *reinterpret_cast<const f32x4*>(&Vg[(size_t)r * HWP_ + kvn + s * 8]);
      }
    }
    // QK^T (swapped): sacc rows kv, col q
    f32x4 sacc[4] = {};
#pragma unroll
    for (int kk = 0; kk < 2; ++kk) {
      bf16x8 kf[4];
#pragma unroll
      for (int i = 0; i < 4; ++i) {
        const int row = i * 16 + q;
        const int sl = (kk * 4 + g) ^ (row & 7);
        kf[i] = *reinterpret_cast<const bf16x8*>(&Ks[row * 64 + sl * 8]);
      }
#pragma unroll
      for (int i = 0; i < 4; ++i) sacc[i] = mfma16(kf[i], qf[kk], sacc[i]);
    }
    // online softmax (log2 domain), defer-max, per-wave
    float tmax = -1e30f;
#pragma unroll
    for (int i = 0; i < 4; ++i)
#pragma unroll
      for (int r = 0; r < 4; ++r) tmax = fmaxf(tmax, sacc[i][r]);
    tmax = fmaxf(tmax, __shfl_xor(tmax, 16));
    tmax = fmaxf(tmax, __shfl_xor(tmax, 32));
    if (__any(tmax > m_run + 11.0f)) {
      const float mnew = fmaxf(m_run, tmax);
      const float alpha = exp2f(m_run - mnew);
      m_run = mnew;
      l_run *= alpha;
      float al[4];
#pragma unroll
      for (int r = 0; r < 4; ++r) al[r] = __shfl(alpha, g * 4 + r);
#pragma unroll
      for (int j = 0; j < 16; ++j) {
        oacc[j][0] *= al[0]; oacc[j][1] *= al[1];
        oacc[j][2] *= al[2]; oacc[j][3] *= al[3];
      }
    }
    float lsum = 0.f;
#pragma unroll
    for (int i = 0; i < 4; ++i) {
      const float p0 = exp2f(sacc[i][0] - m_run);
      const float p1 = exp2f(sacc[i][1] - m_run);
      const float p2 = exp2f(sacc[i][2] - m_run);
      const float p3 = exp2f(sacc[i][3] - m_run);
      lsum += (p0 + p1) + (p2 + p3);
      u32x2 pw;
      pw[0] = ((unsigned)f2b(p1) << 16) | f2b(p0);
      pw[1] = ((unsigned)f2b(p3) << 16) | f2b(p2);
      const int sl = (2 * i + (g >> 1)) ^ (q & 7);   // (kv>>3) ^ (q&7)
      *reinterpret_cast<u32x2*>(&P[q * 64 + sl * 8 + (g & 1) * 4]) = pw;
    }
    lsum += __shfl_xor(lsum, 16);
    lsum += __shfl_xor(lsum, 32);
    l_run += lsum;
    // PV: pa from wave-private LDS; vf from staged LDS
    __builtin_amdgcn_s_setprio(1);
#pragma unroll
    for (int kk = 0; kk < 2; ++kk) {
      const bf16x8 pa = *reinterpret_cast<const bf16x8*>(&P[q * 64 + ((kk * 4 + g) ^ (q & 7)) * 8]);
#pragma unroll
      for (int j = 0; j < 16; ++j) {
        const int row = j * 16 + q;
        const int sl = (kk * 4 + g) ^ (row & 7);
        const bf16x8 vf = *reinterpret_cast<const bf16x8*>(&Vs[row * 64 + sl * 8]);
        oacc[j] = mfma16(pa, vf, oacc[j]);
      }
    }
    __builtin_amdgcn_s_setprio(0);
  }
  // epilogue: normalize, repack to LDS, dwordx4 store
  float linv[4];
  {
    const float myinv = 1.f / l_run;
#pragma unroll
    for (int r = 0; r < 4; ++r) linv[r] = __shfl(myinv, g * 4 + r);
  }
  unsigned short* eps = (unsigned short*)smem;   // 64 x 264 bf16 = 33792B
  __syncthreads();
#pragma unroll
  for (int j = 0; j < 16; ++j)
#pragma unroll
    for (int r = 0; r < 4; ++r) {
      const int row = wid * 16 + g * 4 + r;
      const int cv = j * 16 + q;
      eps[row * 264 + cv] = f2b(oacc[j][r] * linv[r]);
    }
  __syncthreads();
  unsigned short* O = oat + (size_t)b * HW_ * CV_ + (size_t)q0 * CV_;
#pragma unroll
  for (int t = 0; t < 8; ++t) {
    const int row = t * 8 + (tid >> 5);
    const int cv8 = (tid & 31) * 8;
    *reinterpret_cast<f32x4*>(&O[(size_t)row * CV_ + cv8]) =
        *reinterpret_cast<const f32x4*>(&eps[row * 264 + cv8]);
  }
}

// ---------------------------------------------------------------- K5: out[b][co][n] = gamma * wo@Oatt^T + x
__global__ __launch_bounds__(256) void k_gemm_out(
    const unsigned short* __restrict__ oat, const unsigned short* __restrict__ wob,
    const float* __restrict__ x, const float* __restrict__ gamma,
    float* __restrict__ out) {
  __shared__ alignas(16) char smem[32768];
  unsigned short* As = (unsigned short*)smem;
  unsigned short* Bs = (unsigned short*)(smem + 16384);
  const int lid = blockIdx.x;                              // 2048 blocks
  const int swz = (lid & 7) * 256 + (lid >> 3);
  const int ct = swz & 3, nt = (swz >> 2) & 31, b = swz >> 7;
  const int n0 = nt * 128, co0 = ct * 128;
  const unsigned short* Ap = wob + (size_t)co0 * CV_;
  const unsigned short* Bp = oat + (size_t)b * HW_ * CV_ + (size_t)n0 * CV_;
  const int tid = threadIdx.x, lane = tid & 63, wid = tid >> 6;
  const int wc = (wid >> 1) * 64, wn = (wid & 1) * 64;
  f32x4 acc[4][4] = {};
  for (int k0 = 0; k0 < CV_; k0 += 64) {
    __syncthreads();
#pragma unroll
    for (int i = 0; i < 4; ++i) {
      const int r = i * 32 + (tid >> 3);
      const int s = tid & 7, ss = s ^ (r & 7);
      *reinterpret_cast<f32x4*>(&As[r * 64 + ss * 8]) =
          *reinterpret_cast<const f32x4*>(&Ap[(size_t)r * CV_ + k0 + s * 8]);
      *reinterpret_cast<f32x4*>(&Bs[r * 64 + ss * 8]) =
          *reinterpret_cast<const f32x4*>(&Bp[(size_t)r * CV_ + k0 + s * 8]);
    }
    __syncthreads();
#pragma unroll
    for (int kk = 0; kk < 2; ++kk) {
      bf16x8 af[4], bfr[4];
#pragma unroll
      for (int i = 0; i < 4; ++i) {
        const int r = wc + i * 16 + (lane & 15);
        const int slot = (kk * 4 + (lane >> 4)) ^ (r & 7);
        af[i] = *reinterpret_cast<const bf16x8*>(&As[r * 64 + slot * 8]);
      }
#pragma unroll
      for (int j = 0; j < 4; ++j) {
        const int r = wn + j * 16 + (lane & 15);
        const int slot = (kk * 4 + (lane >> 4)) ^ (r & 7);
        bfr[j] = *reinterpret_cast<const bf16x8*>(&Bs[r * 64 + slot * 8]);
      }
#pragma unroll
      for (int i = 0; i < 4; ++i)
#pragma unroll
        for (int j = 0; j < 4; ++j) acc[i][j] = mfma16(af[i], bfr[j], acc[i][j]);
    }
  }
  // epilogue: 4 chunks of 32 co-rows; LDS f32 [32][132]; dwordx4 x-load + out-store
  float* eps = (float*)smem;
  const float g = gamma[0];
  const size_t base = (size_t)b * C_ * HW_;
#pragma unroll
  for (int h = 0; h < 4; ++h) {
    __syncthreads();
    if ((wid >> 1) == (h >> 1)) {
#pragma unroll
      for (int ii = 0; ii < 2; ++ii) {
        const int i = (h & 1) * 2 + ii;
#pragma unroll
        for (int j = 0; j < 4; ++j)
#pragma unroll
          for (int r = 0; r < 4; ++r) {
            const int col2 = ii * 16 + (lane >> 4) * 4 + r;
            const int nl = wn + j * 16 + (lane & 15);
            eps[col2 * 132 + nl] = acc[i][j][r];
          }
      }
    }
    __syncthreads();
#pragma unroll
    for (int t = 0; t < 4; ++t) {
      const int row = t * 8 + (tid >> 5);
      const int col = (tid & 31) * 4;
      const size_t goff = base + (size_t)(co0 + h * 32 + row) * HW_ + n0 + col;
      const f32x4 xv = *reinterpret_cast<const f32x4*>(&x[goff]);
      const f32x4 av = *reinterpret_cast<const f32x4*>(&eps[row * 132 + col]);
      f32x4 ov;
      ov[0] = g * av[0] + xv[0];
      ov[1] = g * av[1] + xv[1];
      ov[2] = g * av[2] + xv[2];
      ov[3] = g * av[3] + xv[3];
      *reinterpret_cast<f32x4*>(&out[goff]) = ov;
    }
  }
}

// ---------------------------------------------------------------- launcher
extern "C" void kernel_launch(void* const* d_in, const int* in_sizes, int n_in,
                              void* d_out, int out_size, void* d_ws, size_t ws_size,
                              hipStream_t stream) {
  (void)in_sizes; (void)n_in; (void)out_size; (void)ws_size;
  const float* x     = (const float*)d_in[0];
  const float* Wq    = (const float*)d_in[1];
  const float* Wk    = (const float*)d_in[2];
  const float* Wv    = (const float*)d_in[3];
  const float* Wo    = (const float*)d_in[4];
  const float* gamma = (const float*)d_in[5];
  float* out = (float*)d_out;
  char* ws = (char*)d_ws;

  unsigned short* wqkv = (unsigned short*)(ws);                 // 384*512*2
  unsigned short* wob  = (unsigned short*)(ws + 393216);        // 512*256*2
  unsigned short* xb   = (unsigned short*)(ws + 655360);        // 64MB
  unsigned short* yt   = (unsigned short*)(ws + 67764224);      // 48MB
  unsigned short* gt   = (unsigned short*)(ws + 118095872);     // 2MB
  unsigned short* vt   = (unsigned short*)(ws + 120193024);     // 8MB
  unsigned short* oat  = xb;  // alias: xb dead after k_gemm_qkv
  float* wt = (float*)yt;     // alias: wT only live during specnorm

  k_wtrans<<<dim3(8, 8, 4), 256, 0, stream>>>(Wq, Wk, Wv, Wo, wt);
  k_specnorm<<<4, 512, 0, stream>>>(Wq, Wk, Wv, Wo, wt, wqkv, wob);
  k_transpose<<<dim3(64, 8, 16), 256, 0, stream>>>(x, xb);
  k_gemm_qkv<<<1536, 256, 0, stream>>>(xb, wqkv, yt);
  k_pool_g<<<dim3(16, 16), 256, 0, stream>>>(yt, gt);
  k_pool_vt<<<dim3(16, 4, 16), 256, 0, stream>>>(yt, vt);
  k_attn<<<1024, 256, 0, stream>>>(yt, gt, vt, oat);
  k_gemm_out<<<2048, 256, 0, stream>>>(oat, wob, x, gamma, out);
}